// Round 5
// baseline (44.824 us; speedup 1.0000x reference)
//
#include <hip/hip_runtime.h>

// Problem constants (from reference)
#define BATCH 16
#define NSEG 32
#define HW (512 * 1024)              // 524288 pixels per batch
#define MIN_PIX 50.0f

// Accum kernel: 1-wave blocks, per-thread float4 bins in LDS, quad-RMW.
#define THREADS 64
#define BLOCKS_PER_BATCH 128
#define QUADS 16                     // HW / (BLOCKS_PER_BATCH*THREADS*4)

// Accumulator layout in d_ws: acc[b][s][4], comp: 0=cnt 1=su 2=sv 3=s2
#define ACC_FLOATS (BATCH * NSEG * 4)

__global__ __launch_bounds__(THREADS) void ovl_accum(
    const float* __restrict__ flow,   // [B, 2, H, W]
    const int* __restrict__ masks,    // [B, H, W]
    float* __restrict__ acc)          // [B, S, 4], pre-zeroed
{
    __shared__ float4 bins[THREADS][NSEG];   // 32 KiB -> 5 blocks/CU

    const int tid = threadIdx.x;
    #pragma unroll
    for (int i = 0; i < NSEG; ++i)
        bins[tid][i] = make_float4(0.0f, 0.0f, 0.0f, 0.0f);
    // single wave per block: lockstep

    const int b  = blockIdx.x >> 7;                      // batch
    const int bk = blockIdx.x & (BLOCKS_PER_BATCH - 1);  // block within batch
    const float* __restrict__ u_base = flow + (size_t)b * 2 * HW;
    const float* __restrict__ v_base = u_base + HW;
    const int*   __restrict__ m_base = masks + (size_t)b * HW;

#define LOADP(S, Q) { const int p = (((Q) * BLOCKS_PER_BATCH + bk) * THREADS + tid) * 4; \
        m##S = *(const int4*)(m_base + p);                                               \
        u##S = *(const float4*)(u_base + p);                                             \
        v##S = *(const float4*)(v_base + p); }

// Quad processing: 4 independent LDS reads -> register dup-merge -> 4 writes
// in descending slot order (in-order DS pipe => live earliest write lands last).
#define PROCQ(mq, uq, vq) {                                                    \
        const int s0 = mq.x & 31, s1 = mq.y & 31, s2 = mq.z & 31, s3 = mq.w & 31; \
        float d0c = 1.0f, d0u = uq.x, d0v = vq.x, d0w = uq.x*uq.x + vq.x*vq.x; \
        float d1c = 1.0f, d1u = uq.y, d1v = vq.y, d1w = uq.y*uq.y + vq.y*vq.y; \
        float d2c = 1.0f, d2u = uq.z, d2v = vq.z, d2w = uq.z*uq.z + vq.z*vq.z; \
        float d3c = 1.0f, d3u = uq.w, d3v = vq.w, d3w = uq.w*uq.w + vq.w*vq.w; \
        const bool m10 = (s1 == s0);                                           \
        const bool m20 = (s2 == s0), m21 = !m20 && (s2 == s1);                 \
        const bool m30 = (s3 == s0), m31 = !m30 && (s3 == s1);                 \
        const bool m32 = !m30 && !m31 && (s3 == s2);                           \
        d0c += m10 ? d1c : 0.0f; d0u += m10 ? d1u : 0.0f;                      \
        d0v += m10 ? d1v : 0.0f; d0w += m10 ? d1w : 0.0f;                      \
        d0c += m20 ? d2c : 0.0f; d0u += m20 ? d2u : 0.0f;                      \
        d0v += m20 ? d2v : 0.0f; d0w += m20 ? d2w : 0.0f;                      \
        d1c += m21 ? d2c : 0.0f; d1u += m21 ? d2u : 0.0f;                      \
        d1v += m21 ? d2v : 0.0f; d1w += m21 ? d2w : 0.0f;                      \
        d0c += m30 ? d3c : 0.0f; d0u += m30 ? d3u : 0.0f;                      \
        d0v += m30 ? d3v : 0.0f; d0w += m30 ? d3w : 0.0f;                      \
        d1c += m31 ? d3c : 0.0f; d1u += m31 ? d3u : 0.0f;                      \
        d1v += m31 ? d3v : 0.0f; d1w += m31 ? d3w : 0.0f;                      \
        d2c += m32 ? d3c : 0.0f; d2u += m32 ? d3u : 0.0f;                      \
        d2v += m32 ? d3v : 0.0f; d2w += m32 ? d3w : 0.0f;                      \
        const float k1 = m10 ? 0.0f : 1.0f;                                    \
        const float k2 = (m20 || m21) ? 0.0f : 1.0f;                           \
        const float k3 = (m30 || m31 || m32) ? 0.0f : 1.0f;                    \
        float4 x0 = bins[tid][s0];                                             \
        float4 x1 = bins[tid][s1];                                             \
        float4 x2 = bins[tid][s2];                                             \
        float4 x3 = bins[tid][s3];                                             \
        x0.x += d0c;      x0.y += d0u;      x0.z += d0v;      x0.w += d0w;     \
        x1.x += k1 * d1c; x1.y += k1 * d1u; x1.z += k1 * d1v; x1.w += k1 * d1w;\
        x2.x += k2 * d2c; x2.y += k2 * d2u; x2.z += k2 * d2v; x2.w += k2 * d2w;\
        x3.x += k3 * d3c; x3.y += k3 * d3u; x3.z += k3 * d3v; x3.w += k3 * d3w;\
        bins[tid][s3] = x3;                                                    \
        bins[tid][s2] = x2;                                                    \
        bins[tid][s1] = x1;                                                    \
        bins[tid][s0] = x0;                                                    \
    }

    int4 mA, mB; float4 uA, vA, uB, vB;
    LOADP(A, 0)
    LOADP(B, 1)
    #pragma unroll
    for (int q = 0; q < QUADS; q += 2) {
        PROCQ(mA, uA, vA)
        if (q + 2 < QUADS) LOADP(A, q + 2)
        PROCQ(mB, uB, vB)
        if (q + 3 < QUADS) LOADP(B, q + 3)
    }

    __syncthreads();

    // Reduce the 64 private rows -> one native global fp32 atomic per
    // (seg,comp) pair (128 per block).
    const float* bf = (const float*)bins;    // [64][128] floats
    #pragma unroll
    for (int h = 0; h < 2; ++h) {
        const int pair = tid + h * 64;       // 0..127 = s*4 + c
        float sum = 0.0f;
        #pragma unroll
        for (int j = 0; j < THREADS; ++j)
            sum += bf[j * (NSEG * 4) + pair];
        unsafeAtomicAdd(&acc[(size_t)b * NSEG * 4 + pair], sum);
    }
}

__global__ __launch_bounds__(BATCH * NSEG) void ovl_finalize(
    const float* __restrict__ acc,   // [B*S, 4]
    float* __restrict__ out)         // scalar
{
    const int tid = threadIdx.x;     // 0..511, one per global segment id
    const float cnt = acc[tid * 4 + 0];
    const float su  = acc[tid * 4 + 1];
    const float sv  = acc[tid * 4 + 2];
    const float s2  = acc[tid * 4 + 3];

    const bool is_bg = (tid & (NSEG - 1)) == 0;
    const bool valid = (cnt >= MIN_PIX) && !is_bg;

    const float safe_cnt = fmaxf(cnt, 1.0f);
    const float denom = fmaxf(cnt - 1.0f, 1.0f);
    const float var_sum = (s2 - (su * su + sv * sv) / safe_cnt) / denom;

    float t = valid ? var_sum : 0.0f;
    float n = valid ? 1.0f : 0.0f;

    #pragma unroll
    for (int off = 32; off >= 1; off >>= 1) {
        t += __shfl_down(t, off, 64);
        n += __shfl_down(n, off, 64);
    }

    __shared__ float st[8], sn[8];
    const int wave = tid >> 6;
    const int lane = tid & 63;
    if (lane == 0) { st[wave] = t; sn[wave] = n; }
    __syncthreads();

    if (tid == 0) {
        float tot = 0.0f, ntot = 0.0f;
        #pragma unroll
        for (int w = 0; w < 8; ++w) { tot += st[w]; ntot += sn[w]; }
        out[0] = (ntot > 0.0f) ? (tot / fmaxf(ntot, 1.0f)) : 0.0f;
    }
}

extern "C" void kernel_launch(void* const* d_in, const int* in_sizes, int n_in,
                              void* d_out, int out_size, void* d_ws, size_t ws_size,
                              hipStream_t stream) {
    const float* flow = (const float*)d_in[0];
    const int* masks  = (const int*)d_in[1];
    float* out = (float*)d_out;
    float* acc = (float*)d_ws;

    hipMemsetAsync(acc, 0, ACC_FLOATS * sizeof(float), stream);

    ovl_accum<<<BATCH * BLOCKS_PER_BATCH, THREADS, 0, stream>>>(flow, masks, acc);
    ovl_finalize<<<1, BATCH * NSEG, 0, stream>>>(acc, out);
}